// Round 1
// baseline (1246.161 us; speedup 1.0000x reference)
//
#include <hip/hip_runtime.h>

// Problem constants
#define L_DIM 8192
#define V_DIM 25
#define C_DIM 256
#define P_DIM 3
#define KSZ 9
#define TILE_T 120          // output t's per block
#define SLOTS 128           // TILE_T + 8 halo
#define SS_STRIDE 27        // odd stride -> conflict-free, room for half1 pad col

// Pack A (3x25x25) into Apad rows of 32 floats, 16B aligned:
//   slots 0..12  = A[pv][0..12]   (half 0)
//   slots 16..27 = A[pv][13..24]  (half 1), slot 28..31 = 0 (harmless pad FMA)
__global__ void prep_A(const float* __restrict__ A, float* __restrict__ Apad) {
    int idx = blockIdx.x * blockDim.x + threadIdx.x;
    if (idx < P_DIM * V_DIM * 32) {
        int slot = idx & 31;
        int pv = idx >> 5;
        float v = 0.f;
        if (slot < 13) v = A[pv * 25 + slot];
        else if (slot >= 16 && slot < 28) v = A[pv * 25 + (slot - 3)];
        Apad[idx] = v;
    }
}

__global__ __launch_bounds__(256, 3) void stgcn_kernel(
    const float* __restrict__ x, const float* __restrict__ Apad,
    float* __restrict__ out)
{
    __shared__ float xs[P_DIM][SLOTS][V_DIM];   // 38400 B, verbatim copy of x window
    __shared__ float ss[SLOTS][SS_STRIDE];      // 13824 B, s tile

    const int tid = threadIdx.x;
    const int tile = blockIdx.x;
    const int c = blockIdx.y;
    const int t0 = tile * TILE_T;
    const int base_t = t0 - (KSZ - 1);          // first staged t (may be <0)

    // ---- Stage x window [base_t, base_t+128) for 3 p's; OOB -> 0 ----
    float* xsf = &xs[0][0][0];
    for (int e = tid; e < P_DIM * SLOTS * V_DIM; e += 256) {
        int p = e / (SLOTS * V_DIM);
        int r = e - p * (SLOTS * V_DIM);
        int t = base_t + r / V_DIM;
        float val = 0.f;
        if (t >= 0 && t < L_DIM) {
            long gidx = (long)(p * C_DIM + c) * (L_DIM * V_DIM)
                      + (long)base_t * V_DIM + r;   // >= 0 whenever t in range
            val = x[gidx];
        }
        xsf[e] = val;
    }
    __syncthreads();

    // ---- Pass 1: s[t][w] = sum_{p,v} x[p][t][v] * A[p][v][w] ----
    // half is wave-uniform (waves 0,1 -> 0; waves 2,3 -> 1); readfirstlane so
    // the compiler proves A addresses uniform -> scalar (s_load) K$ loads.
    const int half = __builtin_amdgcn_readfirstlane(tid >> 7);
    const int tl = tid & (SLOTS - 1);
    const float* Ab = Apad + half * 16;

    float acc[13];
    #pragma unroll
    for (int i = 0; i < 13; i++) acc[i] = 0.f;

    #pragma unroll
    for (int p = 0; p < P_DIM; p++) {
        const float* xrow = &xs[p][tl][0];
        #pragma unroll 5
        for (int v = 0; v < V_DIM; v++) {
            float xv = xrow[v];
            const float* a = Ab + (p * V_DIM + v) * 32;
            #pragma unroll
            for (int w = 0; w < 13; w++)
                acc[w] = fmaf(xv, a[w], acc[w]);   // a[w] in SGPR
        }
    }

    {   // half0 -> cols 0..12, half1 -> cols 13..25 (col 25 is pad, never read)
        float* srow = &ss[tl][half * 13];
        #pragma unroll
        for (int w = 0; w < 13; w++) srow[w] = acc[w];
    }
    __syncthreads();

    // ---- Pass 2: causal 9-tap sliding sum along t, running-window form ----
    if (tid < 250) {
        int w = tid % 25;
        int strip = tid / 25;                    // 10 strips x 12 t's = 120
        int slot0 = strip * 12 + (KSZ - 1);      // slot of first output t
        float sum = 0.f;
        #pragma unroll
        for (int j = 0; j < KSZ; j++) sum += ss[slot0 - (KSZ - 1) + j][w];

        int t = t0 + strip * 12;
        size_t obase = (size_t)c * (L_DIM * V_DIM);
        if (t < L_DIM) out[obase + (size_t)t * V_DIM + w] = sum;
        #pragma unroll
        for (int k = 1; k < 12; k++) {
            sum += ss[slot0 + k][w] - ss[slot0 + k - KSZ][w];
            int tk = t + k;
            if (tk < L_DIM) out[obase + (size_t)tk * V_DIM + w] = sum;
        }
    }
}

extern "C" void kernel_launch(void* const* d_in, const int* in_sizes, int n_in,
                              void* d_out, int out_size, void* d_ws, size_t ws_size,
                              hipStream_t stream) {
    const float* x = (const float*)d_in[0];
    const float* A = (const float*)d_in[1];
    float* outp = (float*)d_out;
    float* Apad = (float*)d_ws;                  // 3*25*32*4 = 9600 B of ws

    hipLaunchKernelGGL(prep_A, dim3(10), dim3(256), 0, stream, A, Apad);

    dim3 grid((L_DIM + TILE_T - 1) / TILE_T, C_DIM);   // (69, 256)
    hipLaunchKernelGGL(stgcn_kernel, grid, dim3(256), 0, stream, x, Apad, outp);
}